// Round 6
// baseline (221.986 us; speedup 1.0000x reference)
//
#include <hip/hip_runtime.h>

// CSConv2D: per-pixel kernel selection from a 25-entry 5x5 bank, depthwise,
// 'same' zero pad. B=8, C=96, H=W=192, fp32.
//
// R9: tap-major, channel-inner conv core. R5-R8 proved the compiler demotes
// ANY long-lived per-lane weight cache (array / asm-pin / named scalars, 50
// or 100 wide -> VGPR_Count 40-80, per-use access cost). R8's amortize-
// across-convs failed because the hoisted values were parked (scratch/AGPR),
// not register-resident. So: require NO long-lived weights. Per staged row:
// load the 5-float x-window for 3 channel slabs (15 loads; each x feeds both
// output rows), then per tap load w once -> 3 adjacent FMAs (one per
// channel) -> dead. 50 weight floats + 90 input floats per phase for 6
// outputs = 23.3 floats/output (R8: ~40). Live set ~40 regs: nothing to
// demote. Weight addresses = 2 loop-invariant LDS base pointers + immediate
// offsets (kills remat addr-arith). LDS-pipe estimate ~44us, HBM floor 32us.
//
// Geometry/scaffolding identical to verified R8: TH=8, RPT=2, CPG=3, 768
// threads, sin_[2][3][12][200]=57.6KB+2.5KB bank, global_load_lds width=16
// staging, 8 phases, s_waitcnt vmcnt(6)+s_barrier (per wave: 3 loads issued
// at phase top, 6 stores after conv; vmcnt(6) retires prior stores + this
// phase's loads, never this phase's stores). Halo cols / OOB rows zeroed
// once, persist.

#define KS 5
#define NB 25
#define HALO 2
#define TH 8                     // output rows per block
#define RPT 2                    // output rows per thread
#define CPG 3                    // channels per phase
#define WID 192
#define HEI 192
#define CH 96
#define NBATCH 8
#define LPAD 4                   // left pad so row data start is 16B-aligned
#define LROW (LPAD + WID + LPAD) // 200 floats per LDS row
#define LH (TH + 2 * HALO)       // 12 staged rows
#define CSPLIT 4
#define CPB (CH / CSPLIT)        // 24 channels per block
#define NTHREADS (WID * (TH / RPT))  // 768 threads = 12 waves
#define HW ((size_t)HEI * WID)

static_assert(CPB % CPG == 0, "phase count integral");
static_assert(NTHREADS <= 1024, "block size limit");

__device__ __forceinline__ void async16(void* lds, const void* g) {
    // Direct global->LDS copy, 16B per lane. LDS dest is wave-uniform base +
    // lane*16 (hardware semantics); we pass the uniform row base.
    __builtin_amdgcn_global_load_lds(
        (const __attribute__((address_space(1))) void*)g,
        (__attribute__((address_space(3))) void*)lds, 16, 0, 0);
}

// x-window load for one staged row across the 3 channel slabs.
#define XL(CUR, I)                                                            \
    {                                                                         \
        const float* xr0 = &sin_[CUR][0][ty2 + (I)][xoff];                    \
        x0_0 = xr0[0]; x0_1 = xr0[1]; x0_2 = xr0[2]; x0_3 = xr0[3];           \
        x0_4 = xr0[4];                                                        \
        const float* xr1 = &sin_[CUR][1][ty2 + (I)][xoff];                    \
        x1_0 = xr1[0]; x1_1 = xr1[1]; x1_2 = xr1[2]; x1_3 = xr1[3];           \
        x1_4 = xr1[4];                                                        \
        const float* xr2 = &sin_[CUR][2][ty2 + (I)][xoff];                    \
        x2_0 = xr2[0]; x2_1 = xr2[1]; x2_2 = xr2[2]; x2_3 = xr2[3];           \
        x2_4 = xr2[4];                                                        \
    }

// Kernel row KI of bucket0 -> output row r0 (acc ?0), all 3 channels.
// Each weight: one LDS read, 3 immediate uses, then dead.
#define W0ROW(KI)                                                             \
    { float w_;                                                               \
      w_ = wb0[(KI)*KS + 0]; a00 += x0_0*w_; a10 += x1_0*w_; a20 += x2_0*w_;  \
      w_ = wb0[(KI)*KS + 1]; a00 += x0_1*w_; a10 += x1_1*w_; a20 += x2_1*w_;  \
      w_ = wb0[(KI)*KS + 2]; a00 += x0_2*w_; a10 += x1_2*w_; a20 += x2_2*w_;  \
      w_ = wb0[(KI)*KS + 3]; a00 += x0_3*w_; a10 += x1_3*w_; a20 += x2_3*w_;  \
      w_ = wb0[(KI)*KS + 4]; a00 += x0_4*w_; a10 += x1_4*w_; a20 += x2_4*w_; }

// Kernel row KI of bucket1 -> output row r0+1 (acc ?1), all 3 channels.
#define W1ROW(KI)                                                             \
    { float w_;                                                               \
      w_ = wb1[(KI)*KS + 0]; a01 += x0_0*w_; a11 += x1_0*w_; a21 += x2_0*w_;  \
      w_ = wb1[(KI)*KS + 1]; a01 += x0_1*w_; a11 += x1_1*w_; a21 += x2_1*w_;  \
      w_ = wb1[(KI)*KS + 2]; a01 += x0_2*w_; a11 += x1_2*w_; a21 += x2_2*w_;  \
      w_ = wb1[(KI)*KS + 3]; a01 += x0_3*w_; a11 += x1_3*w_; a21 += x2_3*w_;  \
      w_ = wb1[(KI)*KS + 4]; a01 += x0_4*w_; a11 += x1_4*w_; a21 += x2_4*w_; }

__global__ __launch_bounds__(NTHREADS, 2) void csconv_kernel(
    const float* __restrict__ in, const float* __restrict__ bank,
    const int* __restrict__ buckets, float* __restrict__ out)
{
    __shared__ float sb[NB * KS * KS];                      // 2.5 KB bank
    __shared__ __align__(16) float sin_[2][CPG][LH][LROW];  // 57.6 KB slabs

    const int tid  = threadIdx.x;
    const int wcol = tid % WID;     // 0..191
    const int ty   = tid / WID;     // 0..3 (row group)
    const int lane = tid & 63;
    const int wv   = tid >> 6;      // wave id 0..11
    const int cg   = blockIdx.x;    // channel group 0..3
    const int ht   = blockIdx.y;    // row tile 0..23
    const int b    = blockIdx.z;    // batch 0..7
    const int h0   = ht * TH;
    const int r0   = h0 + ty * RPT; // first output row this thread owns

    const int c0 = cg * CPB;
    const float* inb  = in  + (size_t)(b * CH + c0) * HW;
    float*       outb = out + (size_t)(b * CH + c0) * HW;

    // --- one-time LDS init ---------------------------------------------
    // Kernel bank: 625 floats, 768 threads -> single shot.
    if (tid < NB * KS * KS) sb[tid] = bank[tid];

    // Zero halo columns 0..3 and 196..199 of all 6 slabs (576 writes).
    // Persist: staging only writes cols 4..195 of in-bounds rows.
    if (tid < 2 * CPG * LH * 8) {
        const int s = tid / (LH * 8), rem = tid % (LH * 8);
        const int r = rem / 8, p = rem % 8;
        const int col = (p < 4) ? p : (WID + p);   // 0..3, 196..199
        sin_[s / CPG][s % CPG][r][col] = 0.0f;
    }
    // Zero out-of-image rows for edge tiles; staging skips them so the
    // zeros persist for every channel.
    if (h0 - HALO < 0) {
        for (int t = tid; t < 2 * CPG * 2 * LROW; t += NTHREADS) {
            const int s = t / (2 * LROW), rem = t % (2 * LROW);
            sin_[s / CPG][s % CPG][rem / LROW][rem % LROW] = 0.0f;
        }
    }
    if (h0 + TH + HALO > HEI) {
        for (int t = tid; t < 2 * CPG * 2 * LROW; t += NTHREADS) {
            const int s = t / (2 * LROW), rem = t % (2 * LROW);
            sin_[s / CPG][s % CPG][LH - 2 + rem / LROW][rem % LROW] = 0.0f;
        }
    }

    // Prologue: async-stage channels 0..2 into buffer 0. 36 row-copies
    // (3 slabs x 12 rows); wave wv does copies 3wv..3wv+2. 48 lanes x 16B
    // cover one 192-float row.
#pragma unroll
    for (int k = 0; k < CPG; ++k) {
        const int m  = CPG * wv + k;      // 0..35
        const int s  = m / LH;            // slab (channel) 0..2
        const int rr = m % LH;            // staged row 0..11
        const int hg = h0 - HALO + rr;
        if (hg >= 0 && hg < HEI && lane < 48)
            async16(&sin_[0][s][rr][LPAD],
                    inb + (size_t)s * HW + (size_t)hg * WID + lane * 4);
    }

    __syncthreads();   // full drain once: bank, zeros, prologue copies

    // Per-thread bucket row pointers into the LDS bank (loop-invariant).
    const int bkt0 = buckets[(b * HEI + r0 + 0) * WID + wcol];
    const int bkt1 = buckets[(b * HEI + r0 + 1) * WID + wcol];
    const float* wb0 = &sb[bkt0 * (KS * KS)];
    const float* wb1 = &sb[bkt1 * (KS * KS)];

    const int ty2  = ty * RPT;
    const int xoff = wcol + (LPAD - HALO);

    // --- main loop: 8 phases of 3 channels ---------------------------------
    for (int c = 0; c < CPB; c += CPG) {
        const int cur = (c / CPG) & 1;
        const bool has_next = (c + CPG < CPB);

        if (has_next) {
            const int nxt = cur ^ 1;
#pragma unroll
            for (int k = 0; k < CPG; ++k) {
                const int m  = CPG * wv + k;
                const int s  = m / LH;
                const int rr = m % LH;
                const int hg = h0 - HALO + rr;
                if (hg >= 0 && hg < HEI && lane < 48)
                    async16(&sin_[nxt][s][rr][LPAD],
                            inb + (size_t)(c + CPG + s) * HW
                                + (size_t)hg * WID + lane * 4);
            }
        }

        // Conv: staged row ty2+I = global row r0-2+I. Output row r0 uses
        // I=0..4 with kernel row I (bucket0); output row r0+1 uses I=1..5
        // with kernel row I-1 (bucket1). x-window shared by both rows and
        // loaded once; each weight read feeds 3 channel-FMAs immediately.
        {
            float a00 = 0.f, a01 = 0.f, a10 = 0.f, a11 = 0.f,
                  a20 = 0.f, a21 = 0.f;
            float x0_0, x0_1, x0_2, x0_3, x0_4;
            float x1_0, x1_1, x1_2, x1_3, x1_4;
            float x2_0, x2_1, x2_2, x2_3, x2_4;

            XL(cur, 0) W0ROW(0)
            XL(cur, 1) W0ROW(1) W1ROW(0)
            XL(cur, 2) W0ROW(2) W1ROW(1)
            XL(cur, 3) W0ROW(3) W1ROW(2)
            XL(cur, 4) W0ROW(4) W1ROW(3)
            XL(cur, 5)          W1ROW(4)

            float* op = outb + (size_t)(c + 0) * HW + (size_t)r0 * WID + wcol;
            op[0] = a00; op[WID] = a01;
            op = outb + (size_t)(c + 1) * HW + (size_t)r0 * WID + wcol;
            op[0] = a10; op[WID] = a11;
            op = outb + (size_t)(c + 2) * HW + (size_t)r0 * WID + wcol;
            op[0] = a20; op[WID] = a21;
        }

        if (has_next) {
            // Program order this phase (per wave): <=3 async loads at the
            // top, then 6 output stores. vmcnt(6) retires (in-order) the
            // prior-phase stores + this phase's loads; this phase's stores
            // stay in flight across the barrier.
            asm volatile("s_waitcnt vmcnt(6)" ::: "memory");
            __builtin_amdgcn_s_barrier();
            asm volatile("" ::: "memory");
        }
    }
}

extern "C" void kernel_launch(void* const* d_in, const int* in_sizes, int n_in,
                              void* d_out, int out_size, void* d_ws, size_t ws_size,
                              hipStream_t stream) {
    const float* in      = (const float*)d_in[0];
    const float* bank    = (const float*)d_in[1];
    const int*   buckets = (const int*)d_in[2];
    float*       out     = (float*)d_out;
    dim3 grid(CSPLIT, HEI / TH, NBATCH);
    csconv_kernel<<<grid, NTHREADS, 0, stream>>>(in, bank, buckets, out);
}